// Round 3
// baseline (16.497 us; speedup 1.0000x reference)
//
#include <hip/hip_runtime.h>

// PromptEncoder (SAM-style), B=2048, N=128 points, D=256.
// out[b,d] = ( sum_n trig_d(f(points[b,n])) + cnt_{-1}*nap[d] + cnt_{1}*pe0[d]
//              + cnt_{0}*pe1[d] + 0.5*(trig_d(c0)+pe2[d] + trig_d(c1)+pe3[d]) ) / 129
// trig_d = sin for d<128, cos for d>=128; f(p) = ((p+0.5)/512 - 1) @ gauss (revolutions)
//
// Structure: 1 block per batch, 4 waves. Wave w: feature j = (w&1)*64+lane,
// point half h = w>>1. Points live in the wave's own lanes (registers) and are
// broadcast via v_readlane in a fully unrolled loop -> no LDS, no barriers,
// no memory ops in the hot loop. One barrier total (partial combine).

#define NFEAT 128
#define N_PTS 128

__device__ __forceinline__ float sin2pi(float t) { return __builtin_amdgcn_sinf(t); }
__device__ __forceinline__ float cos2pi(float t) { return __builtin_amdgcn_cosf(t); }
__device__ __forceinline__ float fract_(float t) { return __builtin_amdgcn_fractf(t); }
__device__ __forceinline__ float rdlane(float v, int l) {
    return __int_as_float(__builtin_amdgcn_readlane(__float_as_int(v), l));
}

__global__ __launch_bounds__(256)
void prompt_encoder_kernel(const float* __restrict__ points,  // [B,N,2]
                           const int*   __restrict__ labels,  // [B,N]
                           const float* __restrict__ boxes,   // [B,4]
                           const float* __restrict__ gauss,   // [2,128]
                           const float* __restrict__ pe0,
                           const float* __restrict__ pe1,
                           const float* __restrict__ pe2,
                           const float* __restrict__ pe3,
                           const float* __restrict__ nap,
                           float* __restrict__ out)           // [B,256]
{
    const int b    = blockIdx.x;
    const int tid  = threadIdx.x;
    const int lane = tid & 63;
    const int w    = tid >> 6;             // wave id 0..3
    const int jf   = (w & 1) * 64 + lane;  // feature 0..127
    const int h    = w >> 1;               // point half 0/1

    __shared__ float ps[4][64];  // per-wave partial sin sums
    __shared__ float pc[4][64];  // per-wave partial cos sums
    __shared__ int   scnt[6];    // [wave 0/1][lab -1,0,1] counts

    // This wave's 64 points, one per lane (registers only).
    float2 p = ((const float2*)points)[(size_t)b * N_PTS + h * 64 + lane];

    // Label counts via ballot (waves 0,1 cover the 128 labels). No atomics.
    if (w < 2) {
        int lab = labels[(size_t)b * N_PTS + w * 64 + lane];
        unsigned long long bm1 = __ballot(lab == -1);
        unsigned long long bz  = __ballot(lab == 0);
        unsigned long long bp1 = __ballot(lab == 1);
        if (lane == 0) {
            scnt[w * 3 + 0] = __popcll(bm1);
            scnt[w * 3 + 1] = __popcll(bz);
            scnt[w * 3 + 2] = __popcll(bp1);
        }
    }

    // Fold normalization into per-feature constants:
    // t = ((px+0.5)/512-1)*g0 + ((py+0.5)/512-1)*g1 = px*G0 + py*G1 + C
    const float a  = 1.0f / 512.0f;
    const float g0 = gauss[jf];
    const float g1 = gauss[NFEAT + jf];
    const float G0 = g0 * a, G1 = g1 * a;
    const float C  = (0.5f * a - 1.0f) * (g0 + g1);

    float ss0 = 0.f, ss1 = 0.f, cs0 = 0.f, cs1 = 0.f;
    #pragma unroll
    for (int l = 0; l < 64; l += 2) {
        float sx0 = rdlane(p.x, l),     sy0 = rdlane(p.y, l);
        float sx1 = rdlane(p.x, l + 1), sy1 = rdlane(p.y, l + 1);
        float t0 = fract_(fmaf(sx0, G0, fmaf(sy0, G1, C)));
        float t1 = fract_(fmaf(sx1, G0, fmaf(sy1, G1, C)));
        ss0 += sin2pi(t0); cs0 += cos2pi(t0);
        ss1 += sin2pi(t1); cs1 += cos2pi(t1);
    }
    ps[w][lane] = ss0 + ss1;
    pc[w][lane] = cs0 + cs1;
    __syncthreads();  // the only barrier: covers partials + counts

    // Epilogue: thread tid owns output channel d = tid.
    const int d   = tid;
    const int j   = d & (NFEAT - 1);
    const int wlo = j >> 6;      // which feature-wave (0: j<64, 1: j>=64)
    const int li  = j & 63;
    float sum = (d < NFEAT) ? (ps[wlo][li] + ps[wlo + 2][li])
                            : (pc[wlo][li] + pc[wlo + 2][li]);

    float cm1 = (float)(scnt[0] + scnt[3]);  // lab == -1 -> nap
    float c0n = (float)(scnt[1] + scnt[4]);  // lab ==  0 -> pe1
    float cp1 = (float)(scnt[2] + scnt[5]);  // lab ==  1 -> pe0
    float delv = cm1 * nap[d] + cp1 * pe0[d] + c0n * pe1[d];

    float gg0 = gauss[j], gg1 = gauss[NFEAT + j];
    float4 bx = ((const float4*)boxes)[b];
    float t0 = fract_(fmaf((bx.x + 0.5f) * a - 1.0f, gg0,
                           ((bx.y + 0.5f) * a - 1.0f) * gg1));
    float t1 = fract_(fmaf((bx.z + 0.5f) * a - 1.0f, gg0,
                           ((bx.w + 0.5f) * a - 1.0f) * gg1));
    float tr0, tr1;
    if (d < NFEAT) { tr0 = sin2pi(t0); tr1 = sin2pi(t1); }  // wave-uniform branch
    else           { tr0 = cos2pi(t0); tr1 = cos2pi(t1); }
    float box = 0.5f * ((tr0 + pe2[d]) + (tr1 + pe3[d]));

    out[(size_t)b * 256 + d] = (sum + delv + box) * (1.0f / (float)(N_PTS + 1));
}

extern "C" void kernel_launch(void* const* d_in, const int* in_sizes, int n_in,
                              void* d_out, int out_size, void* d_ws, size_t ws_size,
                              hipStream_t stream) {
    const float* points = (const float*)d_in[0];
    const int*   labels = (const int*)d_in[1];
    const float* boxes  = (const float*)d_in[2];
    const float* gauss  = (const float*)d_in[3];
    const float* pe0    = (const float*)d_in[4];
    const float* pe1    = (const float*)d_in[5];
    const float* pe2    = (const float*)d_in[6];
    const float* pe3    = (const float*)d_in[7];
    const float* nap    = (const float*)d_in[8];
    float* out = (float*)d_out;

    const int B = in_sizes[2] / 4;  // boxes is [B,4]

    prompt_encoder_kernel<<<B, 256, 0, stream>>>(points, labels, boxes, gauss,
                                                 pe0, pe1, pe2, pe3, nap, out);
}

// Round 4
// 13.688 us; speedup vs baseline: 1.2052x; 1.2052x over previous
//
#include <hip/hip_runtime.h>

// PromptEncoder (SAM-style), B=2048, N=128 points, D=256.
// out[b,d] = ( sum_n trig_d(f(points[b,n])) + cnt_{-1}*nap[d] + cnt_{1}*pe0[d]
//              + cnt_{0}*pe1[d] + 0.5*(trig_d(c0)+pe2[d] + trig_d(c1)+pe3[d]) ) / 129
// trig_d = sin for d<128, cos for d>=128; f(p) = ((p+0.5)/512 - 1) @ gauss (revolutions)
//
// Structure: 1 block/batch, 4 waves. Thread tid handles features (f, f+64),
// f = tid&63, over point-quarter q = tid>>6 (32 points). Points staged in LDS,
// broadcast-read (uniform addr, conflict-free). Phases via v_pk_fma_f32 with
// op_sel broadcasting the point coord into both halves (no splat movs).
// v_sin_f32/v_cos_f32 take revolutions directly; |phase| <= ~8 << 256 (HW
// valid domain) so NO v_fract_f32. Label counts via ballot, no atomics.

#define NFEAT 128
#define N_PTS 128

typedef float v2f __attribute__((ext_vector_type(2)));

__device__ __forceinline__ float sin2pi(float t) { return __builtin_amdgcn_sinf(t); }
__device__ __forceinline__ float cos2pi(float t) { return __builtin_amdgcn_cosf(t); }

// d = fma(splat(c.y), s1, s2) per half (src0 hi broadcast via op_sel)
__device__ __forceinline__ v2f pk_fma_bcast_y(v2f c, v2f s1, v2f s2) {
    v2f d;
    asm("v_pk_fma_f32 %0, %1, %2, %3 op_sel:[1,0,0]"
        : "=v"(d) : "v"(c), "v"(s1), "v"(s2));
    return d;
}
// d = fma(splat(c.x), s1, s2) per half (src0 lo broadcast via op_sel_hi)
__device__ __forceinline__ v2f pk_fma_bcast_x(v2f c, v2f s1, v2f s2) {
    v2f d;
    asm("v_pk_fma_f32 %0, %1, %2, %3 op_sel_hi:[0,1,1]"
        : "=v"(d) : "v"(c), "v"(s1), "v"(s2));
    return d;
}

__global__ __launch_bounds__(256)
void prompt_encoder_kernel(const float* __restrict__ points,  // [B,N,2]
                           const int*   __restrict__ labels,  // [B,N]
                           const float* __restrict__ boxes,   // [B,4]
                           const float* __restrict__ gauss,   // [2,128]
                           const float* __restrict__ pe0,
                           const float* __restrict__ pe1,
                           const float* __restrict__ pe2,
                           const float* __restrict__ pe3,
                           const float* __restrict__ nap,
                           float* __restrict__ out)           // [B,256]
{
    const int b   = blockIdx.x;
    const int tid = threadIdx.x;
    const int f   = tid & 63;   // features f and f+64
    const int q   = tid >> 6;   // point quarter (32 points)

    __shared__ v2f   sc[N_PTS];        // raw points
    __shared__ float ps[4][NFEAT];     // per-quarter sin partials
    __shared__ float pc[4][NFEAT];     // per-quarter cos partials
    __shared__ int   scnt[6];          // [wave 0/1][lab -1,0,1]

    // Stage raw points: row is exactly 256 floats -> one coalesced float/thread.
    ((float*)sc)[tid] = (points + (size_t)b * 2 * N_PTS)[tid];

    // Label counts via ballot (waves 0,1 cover the 128 labels).
    if (q < 2) {
        int lab = labels[(size_t)b * N_PTS + q * 64 + (tid & 63)];
        unsigned long long bm1 = __ballot(lab == -1);
        unsigned long long bz  = __ballot(lab == 0);
        unsigned long long bp1 = __ballot(lab == 1);
        if ((tid & 63) == 0) {
            scnt[q * 3 + 0] = __popcll(bm1);
            scnt[q * 3 + 1] = __popcll(bz);
            scnt[q * 3 + 2] = __popcll(bp1);
        }
    }

    // Per-feature constants, normalization folded in:
    // t = px*G0 + py*G1 + C,  G = g/512,  C = (0.5/512 - 1)*(g0+g1)
    const float a    = 1.0f / 512.0f;
    const float coff = 0.5f * a - 1.0f;
    const float g0l = gauss[f],        g0h = gauss[f + 64];
    const float g1l = gauss[NFEAT + f], g1h = gauss[NFEAT + f + 64];
    v2f G0p; G0p.x = g0l * a;  G0p.y = g0h * a;
    v2f G1p; G1p.x = g1l * a;  G1p.y = g1h * a;
    v2f Cp;  Cp.x  = coff * (g0l + g1l); Cp.y = coff * (g0h + g1h);

    __syncthreads();

    float ssl = 0.f, csl = 0.f, ssh = 0.f, csh = 0.f;
    const v2f* scq = &sc[q * 32];
    #pragma unroll
    for (int n = 0; n < 32; ++n) {
        v2f c  = scq[n];                        // broadcast ds_read_b64
        v2f u  = pk_fma_bcast_y(c, G1p, Cp);    // py*G1 + C   (both features)
        v2f t2 = pk_fma_bcast_x(c, G0p, u);     // px*G0 + u
        ssl += sin2pi(t2.x); csl += cos2pi(t2.x);
        ssh += sin2pi(t2.y); csh += cos2pi(t2.y);
    }
    ps[q][f] = ssl; ps[q][f + 64] = ssh;
    pc[q][f] = csl; pc[q][f + 64] = csh;
    __syncthreads();  // covers partials + counts

    // Epilogue: thread tid owns output channel d = tid (coalesced store).
    const int d = tid;
    const int j = d & (NFEAT - 1);
    float sum = (d < NFEAT) ? (ps[0][j] + ps[1][j] + ps[2][j] + ps[3][j])
                            : (pc[0][j] + pc[1][j] + pc[2][j] + pc[3][j]);

    float cm1 = (float)(scnt[0] + scnt[3]);  // lab == -1 -> nap
    float c0n = (float)(scnt[1] + scnt[4]);  // lab ==  0 -> pe1
    float cp1 = (float)(scnt[2] + scnt[5]);  // lab ==  1 -> pe0
    float delv = cm1 * nap[d] + cp1 * pe0[d] + c0n * pe1[d];

    float gg0 = gauss[j], gg1 = gauss[NFEAT + j];
    float4 bx = ((const float4*)boxes)[b];
    float t0 = fmaf(fmaf(bx.x, a, coff), gg0, fmaf(bx.y, a, coff) * gg1);
    float t1 = fmaf(fmaf(bx.z, a, coff), gg0, fmaf(bx.w, a, coff) * gg1);
    float tr0, tr1;
    if (d < NFEAT) { tr0 = sin2pi(t0); tr1 = sin2pi(t1); }  // wave-uniform branch
    else           { tr0 = cos2pi(t0); tr1 = cos2pi(t1); }
    float box = 0.5f * ((tr0 + pe2[d]) + (tr1 + pe3[d]));

    out[(size_t)b * 256 + d] = (sum + delv + box) * (1.0f / (float)(N_PTS + 1));
}

extern "C" void kernel_launch(void* const* d_in, const int* in_sizes, int n_in,
                              void* d_out, int out_size, void* d_ws, size_t ws_size,
                              hipStream_t stream) {
    const float* points = (const float*)d_in[0];
    const int*   labels = (const int*)d_in[1];
    const float* boxes  = (const float*)d_in[2];
    const float* gauss  = (const float*)d_in[3];
    const float* pe0    = (const float*)d_in[4];
    const float* pe1    = (const float*)d_in[5];
    const float* pe2    = (const float*)d_in[6];
    const float* pe3    = (const float*)d_in[7];
    const float* nap    = (const float*)d_in[8];
    float* out = (float*)d_out;

    const int B = in_sizes[2] / 4;  // boxes is [B,4]

    prompt_encoder_kernel<<<B, 256, 0, stream>>>(points, labels, boxes, gauss,
                                                 pe0, pe1, pe2, pe3, nap, out);
}